// Round 1
// baseline (46295.761 us; speedup 1.0000x reference)
//
#include <hip/hip_runtime.h>
#include <cmath>

#define TPB 192

// Unified 24x24-output-tile conv3x3 (SAME, stride 1), fp32.
// MODE 0: deform conv1 — input gathered from src/tgt patches, zero pad at patch border
// MODE 1: patch conv   — input from D buffer [patch][CI][24][24], zero pad at patch border
// MODE 2: image conv   — input from A buffer [CI][192][192] (one batch), zero pad at image edge
// MODE 3: image conv   — input gathered from src/tgt concat (one batch), zero pad at image edge
// ACT 0: relu, 1: sigmoid, 2: tanh
template<int MODE, int ACT, int CI_T, int CO_T>
__global__ __launch_bounds__(TPB)
void conv24(const float* __restrict__ in,
            const float* __restrict__ src,
            const float* __restrict__ tgt,
            const float* __restrict__ Wg,
            const float* __restrict__ Bg,
            float* __restrict__ out,
            int CI, int CO, int p0)
{
    __shared__ float sIn[CI_T][676];        // 26x26 padded tile per input channel
    __shared__ float sW[CO_T][CI_T * 9];

    const int t = threadIdx.x;
    const int x = t % 24;
    const int ybase = t / 24;               // 0..7 ; pixels y = ybase + 8*k
    const int co0 = blockIdx.y * CO_T;

    int b = 0, pi = 0, pj = 0, ty = 0, tx = 0;
    if (MODE == 0) {
        int P = p0 + blockIdx.x;            // global patch id in [0,450)
        b = P / 225; int rem = P % 225; pi = rem / 15; pj = rem % 15;
    } else if (MODE >= 2) {
        b = p0; ty = blockIdx.x / 8; tx = blockIdx.x % 8;
    }

    float acc[CO_T][3];
    #pragma unroll
    for (int c = 0; c < CO_T; ++c) { acc[c][0] = 0.f; acc[c][1] = 0.f; acc[c][2] = 0.f; }

    for (int ci0 = 0; ci0 < CI; ci0 += CI_T) {
        __syncthreads();
        // ---- stage input tile ----
        for (int idx = t; idx < CI_T * 676; idx += TPB) {
            int ci_l = idx / 676; int r = idx % 676;
            int yy = r / 26, xx = r % 26;
            float v = 0.f;
            if (MODE == 0) {
                if (yy >= 1 && yy <= 24 && xx >= 1 && xx <= 24) {
                    int ci = ci0 + ci_l;
                    const float* img = (ci < 64) ? src : tgt;
                    v = img[((size_t)b * 64 + (ci & 63)) * 36864
                            + (size_t)(pi * 12 + yy - 1) * 192 + (pj * 12 + xx - 1)];
                }
            } else if (MODE == 1) {
                if (yy >= 1 && yy <= 24 && xx >= 1 && xx <= 24) {
                    v = in[((size_t)blockIdx.x * CI + ci0 + ci_l) * 576 + (yy - 1) * 24 + (xx - 1)];
                }
            } else {
                int Y = ty * 24 + yy - 1, X = tx * 24 + xx - 1;
                if (Y >= 0 && Y < 192 && X >= 0 && X < 192) {
                    if (MODE == 2) {
                        v = in[(size_t)(ci0 + ci_l) * 36864 + Y * 192 + X];
                    } else {
                        int ci = ci0 + ci_l;
                        const float* img = (ci < 64) ? src : tgt;
                        v = img[((size_t)b * 64 + (ci & 63)) * 36864 + Y * 192 + X];
                    }
                }
            }
            sIn[ci_l][r] = v;
        }
        // ---- stage weights ----
        for (int idx = t; idx < CO_T * CI_T * 9; idx += TPB) {
            int co_l = idx / (CI_T * 9); int r = idx % (CI_T * 9);
            int ci_l = r / 9; int k = r % 9;
            sW[co_l][r] = Wg[((size_t)(co0 + co_l) * CI + ci0 + ci_l) * 9 + k];
        }
        __syncthreads();
        // ---- compute ----
        for (int ci_l = 0; ci_l < CI_T; ++ci_l) {
            float iv[3][9];
            const float* sp = &sIn[ci_l][0];
            #pragma unroll
            for (int k3 = 0; k3 < 3; ++k3) {
                int y = ybase + 8 * k3;
                #pragma unroll
                for (int ky = 0; ky < 3; ++ky)
                    #pragma unroll
                    for (int kx = 0; kx < 3; ++kx)
                        iv[k3][ky * 3 + kx] = sp[(y + ky) * 26 + (x + kx)];
            }
            #pragma unroll
            for (int co_l = 0; co_l < CO_T; ++co_l) {
                const float* wp = &sW[co_l][ci_l * 9];
                float w[9];
                #pragma unroll
                for (int k = 0; k < 9; ++k) w[k] = wp[k];
                #pragma unroll
                for (int k3 = 0; k3 < 3; ++k3) {
                    float s = acc[co_l][k3];
                    #pragma unroll
                    for (int k = 0; k < 9; ++k) s = fmaf(iv[k3][k], w[k], s);
                    acc[co_l][k3] = s;
                }
            }
        }
    }

    // ---- epilogue ----
    #pragma unroll
    for (int co_l = 0; co_l < CO_T; ++co_l) {
        float bias = Bg[co0 + co_l];
        #pragma unroll
        for (int k3 = 0; k3 < 3; ++k3) {
            float v = acc[co_l][k3] + bias;
            if (ACT == 0)      v = fmaxf(v, 0.f);
            else if (ACT == 1) v = 1.f / (1.f + expf(-v));
            else               v = tanhf(v);
            int y = ybase + 8 * k3;
            if (MODE <= 1) {
                out[((size_t)blockIdx.x * CO + co0 + co_l) * 576 + y * 24 + x] = v;
            } else {
                out[(size_t)(co0 + co_l) * 36864 + (size_t)(ty * 24 + y) * 192 + (tx * 24 + x)] = v;
            }
        }
    }
}

// attention overlap-add: coverage count is closed-form ({1,2} per axis)
__global__ __launch_bounds__(256)
void att_finalize(const float* __restrict__ score, float* __restrict__ out)
{
    int idx = blockIdx.x * 256 + threadIdx.x;
    if (idx >= 2 * 36864) return;
    int b = idx / 36864; int r = idx % 36864;
    int y = r / 192, x = r % 192;
    int i_lo = (y >= 24) ? (y - 12) / 12 : 0;
    int i_hi = min(14, y / 12);
    int j_lo = (x >= 24) ? (x - 12) / 12 : 0;
    int j_hi = min(14, x / 12);
    float s = 0.f; int cnt = 0;
    for (int i = i_lo; i <= i_hi; ++i)
        for (int j = j_lo; j <= j_hi; ++j) {
            s += score[(((size_t)b * 15 + i) * 15 + j) * 576 + (y - 12 * i) * 24 + (x - 12 * j)];
            ++cnt;
        }
    out[idx] = s / (float)cnt;
}

extern "C" void kernel_launch(void* const* d_in, const int* in_sizes, int n_in,
                              void* d_out, int out_size, void* d_ws, size_t ws_size,
                              hipStream_t stream)
{
    const float* src = (const float*)d_in[0];
    const float* tgt = (const float*)d_in[1];
    const float* W1  = (const float*)d_in[2];  const float* b1  = (const float*)d_in[3];
    const float* W2  = (const float*)d_in[4];  const float* b2  = (const float*)d_in[5];
    const float* W3  = (const float*)d_in[6];  const float* b3  = (const float*)d_in[7];
    const float* Wr1 = (const float*)d_in[8];  const float* br1 = (const float*)d_in[9];
    const float* Wr2 = (const float*)d_in[10]; const float* br2 = (const float*)d_in[11];
    const float* Wr3 = (const float*)d_in[12]; const float* br3 = (const float*)d_in[13];
    float* out = (float*)d_out;

    // workspace layout (floats):
    //  score : 450*576                      =   259,200
    //  region: max(D1+D2 for 50-patch chunk, A1+A2 per batch)
    //    D1 = 50*512*576 = 14,745,600 ; D2 = 50*256*576 = 7,372,800
    //    A1 = 512*36864  = 18,874,368 ; A2 = 64*36864   = 2,359,296
    //  total ≈ 22.4M floats ≈ 90 MB
    float* ws    = (float*)d_ws;
    float* score = ws;
    float* region = ws + 259200;
    float* D1 = region;
    float* D2 = D1 + (size_t)50 * 512 * 576;
    float* A1 = region;                      // reused after deform path completes
    float* A2 = A1 + (size_t)512 * 36864;

    // ---- deform/attention path: 9 chunks of 50 patches ----
    for (int c = 0; c < 9; ++c) {
        int p0 = c * 50;
        conv24<0, 0, 16, 16><<<dim3(50, 32), TPB, 0, stream>>>(
            nullptr, src, tgt, W1, b1, D1, 128, 512, p0);
        conv24<1, 0, 16, 16><<<dim3(50, 16), TPB, 0, stream>>>(
            D1, nullptr, nullptr, W2, b2, D2, 512, 256, 0);
        conv24<1, 1, 16, 1><<<dim3(50, 1), TPB, 0, stream>>>(
            D2, nullptr, nullptr, W3, b3, score + (size_t)p0 * 576, 256, 1, 0);
    }
    att_finalize<<<(2 * 36864 + 255) / 256, 256, 0, stream>>>(score, out + 73728);

    // ---- registration path: per batch ----
    for (int b = 0; b < 2; ++b) {
        conv24<3, 0, 16, 16><<<dim3(64, 32), TPB, 0, stream>>>(
            nullptr, src, tgt, Wr1, br1, A1, 128, 512, b);
        conv24<2, 0, 16, 16><<<dim3(64, 4), TPB, 0, stream>>>(
            A1, nullptr, nullptr, Wr2, br2, A2, 512, 64, b);
        conv24<2, 2, 16, 1><<<dim3(64, 1), TPB, 0, stream>>>(
            A2, nullptr, nullptr, Wr3, br3, out + (size_t)b * 36864, 64, 1, b);
    }
}

// Round 2
// 4118.421 us; speedup vs baseline: 11.2411x; 11.2411x over previous
//
#include <hip/hip_runtime.h>
#include <cmath>

typedef _Float16 half8  __attribute__((ext_vector_type(8)));
typedef _Float16 half4v __attribute__((ext_vector_type(4)));
typedef float    float4v __attribute__((ext_vector_type(4)));

// ---------------------------------------------------------------------------
// MFMA conv3x3 (SAME), fp16 in / fp32 acc / fp16 out (relu).
// Inputs are PRE-PADDED NHWC fp16: padded pixel (0,0) corresponds to output
// pixel (-1,-1); guard ring holds zeros (or real halo for image mode — both
// are just data here, no predicates).
// WG = 256 thr = 4 waves, tile = 64 co x 576 px (24x24).
// Wave tile = 64 co x 144 px = 4 m-tiles x 9 n-tiles of 16x16 MFMA C-frags.
// A (weights) from LDS [tap][64 co][32 ci]; B (pixels) direct from global.
// ---------------------------------------------------------------------------
__global__ __launch_bounds__(256, 2)
void mfma_conv(const _Float16* __restrict__ in, const _Float16* __restrict__ Wg,
               const float* __restrict__ bias, _Float16* __restrict__ out,
               int CI, int CO, int RSin, int RSout, int IMG)
{
    __shared__ __align__(16) _Float16 sW[9 * 64 * 32];   // 36,864 B

    const int tid  = threadIdx.x;
    const int wave = tid >> 6;
    const int lane = tid & 63;
    const int ll   = lane & 15;          // n-col / a-row index
    const int quad = lane >> 4;          // k-group
    const int co0  = blockIdx.y * 64;
    const int bx   = blockIdx.x;

    size_t in_base, out_base;
    if (IMG) {
        int ty = bx >> 3, tx = bx & 7;
        in_base  = (size_t)(ty * 24 * RSin  + tx * 24) * CI;
        out_base = (size_t)(ty * 24 * RSout + tx * 24) * CO;
    } else {
        in_base  = (size_t)bx * 676 * CI;
        out_base = (size_t)bx * 676 * CO;
    }

    int b_off[9];
    #pragma unroll
    for (int nt = 0; nt < 9; ++nt) {
        int p = wave * 144 + nt * 16 + ll;
        b_off[nt] = (p / 24) * RSin * CI + (p % 24) * CI;
    }
    int tapoff[9];
    #pragma unroll
    for (int dy = 0; dy < 3; ++dy)
        #pragma unroll
        for (int dx = 0; dx < 3; ++dx)
            tapoff[dy * 3 + dx] = (dy * RSin + dx) * CI;

    float4v acc[4][9];
    #pragma unroll
    for (int mt = 0; mt < 4; ++mt)
        #pragma unroll
        for (int nt = 0; nt < 9; ++nt)
            acc[mt][nt] = (float4v){0.f, 0.f, 0.f, 0.f};

    for (int ci0 = 0; ci0 < CI; ci0 += 32) {
        __syncthreads();
        // stage weights: 9 taps x 64 co x 32 ci  (2304 x 16B chunks)
        for (int c = tid; c < 9 * 64 * 4; c += 256) {
            int q = c & 3, tco = c >> 2;
            int t = tco >> 6, co_l = tco & 63;
            *(uint4*)&sW[tco * 32 + q * 8] =
                *(const uint4*)&Wg[((size_t)(co0 + co_l) * 9 + t) * CI + ci0 + q * 8];
        }
        __syncthreads();

        const _Float16* inp = in + in_base + ci0 + quad * 8;
        #pragma unroll
        for (int t = 0; t < 9; ++t) {
            half8 a[4];
            #pragma unroll
            for (int mt = 0; mt < 4; ++mt)
                a[mt] = *(const half8*)&sW[(t * 64 + mt * 16 + ll) * 32 + quad * 8];
            const int toff = tapoff[t];
            #pragma unroll
            for (int nt = 0; nt < 9; ++nt) {
                half8 b = *(const half8*)(inp + b_off[nt] + toff);
                #pragma unroll
                for (int mt = 0; mt < 4; ++mt)
                    acc[mt][nt] = __builtin_amdgcn_mfma_f32_16x16x32_f16(
                        a[mt], b, acc[mt][nt], 0, 0, 0);
            }
        }
    }

    // epilogue: bias + relu -> fp16, D layout col=lane&15 (px), row=quad*4+reg (co)
    #pragma unroll
    for (int mt = 0; mt < 4; ++mt) {
        float4v bs = *(const float4v*)&bias[co0 + mt * 16 + quad * 4];
        #pragma unroll
        for (int nt = 0; nt < 9; ++nt) {
            int p = wave * 144 + nt * 16 + ll;
            size_t ooff = out_base
                + (size_t)((p / 24 + 1) * RSout + (p % 24) + 1) * CO
                + co0 + mt * 16 + quad * 4;
            float4v v = acc[mt][nt];
            half4v h;
            h.x = (_Float16)fmaxf(v.x + bs.x, 0.f);
            h.y = (_Float16)fmaxf(v.y + bs.y, 0.f);
            h.z = (_Float16)fmaxf(v.z + bs.z, 0.f);
            h.w = (_Float16)fmaxf(v.w + bs.w, 0.f);
            *(half4v*)(out + ooff) = h;
        }
    }
}

// ---------------------------------------------------------------------------
// helpers
// ---------------------------------------------------------------------------
// fp32 NCHW src/tgt -> padded NHWC fp16 image [2][194][194][128] (ring pre-zeroed)
__global__ __launch_bounds__(256)
void build_x16i(const float* __restrict__ src, const float* __restrict__ tgt,
                _Float16* __restrict__ X)
{
    int idx = blockIdx.x * 256 + threadIdx.x;
    int q = idx & 15, pid = idx >> 4;
    if (pid >= 2 * 36864) return;
    int b = pid / 36864, r = pid % 36864;
    int y = r / 192, x = r % 192;
    half8 h;
    #pragma unroll
    for (int j = 0; j < 8; ++j) {
        int ch = q * 8 + j;
        const float* im = (ch < 64) ? src : tgt;
        h[j] = (_Float16)im[(size_t)(b * 64 + (ch & 63)) * 36864 + r];
    }
    *(half8*)&X[(((size_t)b * 194 + y + 1) * 194 + (x + 1)) * 128 + q * 8] = h;
}

// fp32 OIHW -> fp16 [co][tap][ci]
__global__ __launch_bounds__(256)
void cvt_w(const float* __restrict__ src, _Float16* __restrict__ dst, int CO, int CI)
{
    int idx = blockIdx.x * 256 + threadIdx.x;
    if (idx >= CO * 9 * CI) return;
    int ci = idx % CI, t = (idx / CI) % 9, co = idx / (9 * CI);
    dst[idx] = (_Float16)src[((size_t)co * CI + ci) * 9 + t];
}

// gather 50 patches from padded image into padded per-patch buffer (zero ring)
__global__ __launch_bounds__(256)
void g_patch(const _Float16* __restrict__ X, _Float16* __restrict__ P1, int p0)
{
    int idx = blockIdx.x * 256 + threadIdx.x;
    if (idx >= 50 * 676 * 16) return;
    int q = idx & 15, t2 = idx >> 4;
    int r676 = t2 % 676, pl = t2 / 676;
    int pr = r676 / 26, pc = r676 % 26;
    int P = p0 + pl;
    int b = P / 225, rem = P % 225, pi = rem / 15, pj = rem % 15;
    uint4 v = {0u, 0u, 0u, 0u};
    if (pr >= 1 && pr <= 24 && pc >= 1 && pc <= 24)
        v = *(const uint4*)&X[(((size_t)b * 194 + pi * 12 + pr) * 194 + (pj * 12 + pc)) * 128 + q * 8];
    *(uint4*)&P1[((size_t)pl * 676 + r676) * 128 + q * 8] = v;
}

// zero the guard ring of a padded NHWC buffer [npatch][RS][RS][CI]
__global__ __launch_bounds__(256)
void ring_zero(_Float16* __restrict__ buf, int npatch, int RS, int CI)
{
    int c8 = CI >> 3;
    int RC = 2 * RS + 2 * (RS - 2);
    int idx = blockIdx.x * 256 + threadIdx.x;
    if (idx >= npatch * RC * c8) return;
    int q = idx % c8, rp = (idx / c8) % RC, pl = idx / (c8 * RC);
    int r, c;
    if (rp < RS)            { r = 0;      c = rp; }
    else if (rp < 2 * RS)   { r = RS - 1; c = rp - RS; }
    else {
        int s = rp - 2 * RS, half = RS - 2;
        if (s < half) { r = s + 1;        c = 0; }
        else          { r = s - half + 1; c = RS - 1; }
    }
    uint4 z = {0u, 0u, 0u, 0u};
    *(uint4*)&buf[((size_t)pl * RS * RS + r * RS + c) * CI + q * 8] = z;
}

// conv3 (M=1) sigmoid over padded D2 [50][26][26][256] -> score fp32
__global__ __launch_bounds__(256)
void conv3_sig(const _Float16* __restrict__ D2, const _Float16* __restrict__ W3h,
               const float* __restrict__ b3, float* __restrict__ score, int p0)
{
    int idx = blockIdx.x * 256 + threadIdx.x;
    if (idx >= 50 * 576) return;
    int pl = idx / 576, p = idx % 576, py = p / 24, px = p % 24;
    float acc = b3[0];
    for (int dy = 0; dy < 3; ++dy)
        for (int dx = 0; dx < 3; ++dx) {
            const _Float16* base = D2 + ((size_t)pl * 676 + (py + dy) * 26 + (px + dx)) * 256;
            const _Float16* wb = W3h + (dy * 3 + dx) * 256;
            for (int c = 0; c < 256; c += 8) {
                half8 v = *(const half8*)(base + c);
                half8 w = *(const half8*)(wb + c);
                #pragma unroll
                for (int j = 0; j < 8; ++j) acc += (float)v[j] * (float)w[j];
            }
        }
    score[(size_t)(p0 + pl) * 576 + p] = 1.f / (1.f + expf(-acc));
}

// conv3 (M=1) tanh over padded A2 [194][194][64] -> out fp32 (one batch)
__global__ __launch_bounds__(256)
void conv3_tanh(const _Float16* __restrict__ A2, const _Float16* __restrict__ Wh,
                const float* __restrict__ br3, float* __restrict__ out)
{
    int idx = blockIdx.x * 256 + threadIdx.x;
    if (idx >= 36864) return;
    int y = idx / 192, x = idx % 192;
    float acc = br3[0];
    for (int dy = 0; dy < 3; ++dy)
        for (int dx = 0; dx < 3; ++dx) {
            const _Float16* base = A2 + ((size_t)(y + dy) * 194 + (x + dx)) * 64;
            const _Float16* wb = Wh + (dy * 3 + dx) * 64;
            for (int c = 0; c < 64; c += 8) {
                half8 v = *(const half8*)(base + c);
                half8 w = *(const half8*)(wb + c);
                #pragma unroll
                for (int j = 0; j < 8; ++j) acc += (float)v[j] * (float)w[j];
            }
        }
    out[idx] = tanhf(acc);
}

// overlap-add normalize (coverage closed-form)
__global__ __launch_bounds__(256)
void att_finalize(const float* __restrict__ score, float* __restrict__ out)
{
    int idx = blockIdx.x * 256 + threadIdx.x;
    if (idx >= 2 * 36864) return;
    int b = idx / 36864, r = idx % 36864;
    int y = r / 192, x = r % 192;
    int i_lo = (y >= 24) ? (y - 12) / 12 : 0;
    int i_hi = min(14, y / 12);
    int j_lo = (x >= 24) ? (x - 12) / 12 : 0;
    int j_hi = min(14, x / 12);
    float s = 0.f; int cnt = 0;
    for (int i = i_lo; i <= i_hi; ++i)
        for (int j = j_lo; j <= j_hi; ++j) {
            s += score[(((size_t)b * 15 + i) * 15 + j) * 576 + (y - 12 * i) * 24 + (x - 12 * j)];
            ++cnt;
        }
    out[idx] = s / (float)cnt;
}

// ---------------------------------------------------------------------------
extern "C" void kernel_launch(void* const* d_in, const int* in_sizes, int n_in,
                              void* d_out, int out_size, void* d_ws, size_t ws_size,
                              hipStream_t stream)
{
    const float* src = (const float*)d_in[0];
    const float* tgt = (const float*)d_in[1];
    const float* W1  = (const float*)d_in[2];  const float* b1  = (const float*)d_in[3];
    const float* W2  = (const float*)d_in[4];  const float* b2  = (const float*)d_in[5];
    const float* W3  = (const float*)d_in[6];  const float* b3  = (const float*)d_in[7];
    const float* Wr1 = (const float*)d_in[8];  const float* br1 = (const float*)d_in[9];
    const float* Wr2 = (const float*)d_in[10]; const float* br2 = (const float*)d_in[11];
    const float* Wr3 = (const float*)d_in[12]; const float* br3 = (const float*)d_in[13];
    float* out = (float*)d_out;

    // ---- workspace layout (halves), total 86.2 MB ----
    _Float16* ws = (_Float16*)d_ws;
    size_t o = 0;
    _Float16* X16i = ws + o; o += (size_t)2 * 194 * 194 * 128;   // 9,634,816
    _Float16* W1h  = ws + o; o += (size_t)512 * 9 * 128;          //   589,824
    _Float16* W2h  = ws + o; o += (size_t)256 * 9 * 512;          // 1,179,648
    _Float16* Wr1h = ws + o; o += (size_t)512 * 9 * 128;
    _Float16* Wr2h = ws + o; o += (size_t)64 * 9 * 512;           //   294,912
    _Float16* W3h  = ws + o; o += 9 * 256;
    _Float16* Wr3h = ws + o; o += 9 * 64;
    float*    score = (float*)(ws + o); o += 2 * 259200;          // fp32 area
    _Float16* P1 = ws + o;                                        // chunk region
    _Float16* D1 = P1 + (size_t)50 * 676 * 128;
    _Float16* D2 = D1 + (size_t)50 * 676 * 512;
    _Float16* A1 = P1;                                            // reg region (reuse)
    _Float16* A2 = A1 + (size_t)194 * 194 * 512;

    // ---- precompute fp16 operands ----
    hipMemsetAsync(X16i, 0, (size_t)2 * 194 * 194 * 128 * 2, stream);
    build_x16i<<<4608, 256, 0, stream>>>(src, tgt, X16i);
    cvt_w<<<2304, 256, 0, stream>>>(W1,  W1h,  512, 128);
    cvt_w<<<4608, 256, 0, stream>>>(W2,  W2h,  256, 512);
    cvt_w<<<2304, 256, 0, stream>>>(Wr1, Wr1h, 512, 128);
    cvt_w<<<1152, 256, 0, stream>>>(Wr2, Wr2h, 64,  512);
    cvt_w<<<9,    256, 0, stream>>>(W3,  W3h,  1,   256);
    cvt_w<<<3,    256, 0, stream>>>(Wr3, Wr3h, 1,   64);

    // ---- attention path: 9 chunks of 50 patches ----
    for (int c = 0; c < 9; ++c) {
        int p0 = c * 50;
        ring_zero<<<1250, 256, 0, stream>>>(D1, 50, 26, 512);
        ring_zero<<<625,  256, 0, stream>>>(D2, 50, 26, 256);
        g_patch<<<2113, 256, 0, stream>>>(X16i, P1, p0);
        mfma_conv<<<dim3(50, 8), 256, 0, stream>>>(P1, W1h, b1, D1, 128, 512, 26, 26, 0);
        mfma_conv<<<dim3(50, 4), 256, 0, stream>>>(D1, W2h, b2, D2, 512, 256, 26, 26, 0);
        conv3_sig<<<113, 256, 0, stream>>>(D2, W3h, b3, score, p0);
    }
    att_finalize<<<288, 256, 0, stream>>>(score, out + 73728);

    // ---- registration path: per batch ----
    for (int b = 0; b < 2; ++b) {
        ring_zero<<<194, 256, 0, stream>>>(A1, 1, 194, 512);
        ring_zero<<<25,  256, 0, stream>>>(A2, 1, 194, 64);
        mfma_conv<<<dim3(64, 8), 256, 0, stream>>>(X16i + (size_t)b * 194 * 194 * 128,
                                                   Wr1h, br1, A1, 128, 512, 194, 194, 1);
        mfma_conv<<<dim3(64, 1), 256, 0, stream>>>(A1, Wr2h, br2, A2, 512, 64, 194, 194, 1);
        conv3_tanh<<<144, 256, 0, stream>>>(A2, Wr3h, br3, out + b * 36864);
    }
}